// Round 18
// baseline (78.247 us; speedup 1.0000x reference)
//
#include <hip/hip_runtime.h>
#include <hip/hip_bf16.h>

#define N_B   4
#define C_IN  128
#define HWSZ  4096
#define C_M   256

typedef __attribute__((ext_vector_type(8)))  short          s16x8;
typedef __attribute__((ext_vector_type(8)))  unsigned short u16x8;
typedef __attribute__((ext_vector_type(4)))  unsigned short u16x4;
typedef __attribute__((ext_vector_type(4)))  float          f32x4;
typedef __attribute__((ext_vector_type(16))) float          f32x16;

__device__ __forceinline__ unsigned short f2bf(float f) {
    union { float f; unsigned u; } v; v.f = f;
    unsigned r = v.u + 0x7fffu + ((v.u >> 16) & 1u);   // RNE
    return (unsigned short)(r >> 16);
}
__device__ __forceinline__ float bf2f(unsigned short u) {
    union { unsigned u; float f; } v; v.u = ((unsigned)u) << 16; return v.f;
}

// ---------------------------------------------------------------------------
// K1: fused prep. Blocks 0..255: img transpose. Blocks 256+: weights.
//  w1f[z2][cc4][tap9][g9][lane64][j8] (unchanged, 16x16 frags for conv1)
//  w2a 32x32-A-frag order [uvt16][t5][ks16 16][lane64][j8]:
//    m = t*32 + (lane&31); k9 = t*2 + ((lane>>4)&1); uv = lane&15;
//    c = ks16*16 + (lane>>5)*8 + j;
//    val = k9<9 ? 0.25*mk_w2[(k9*256 + uvt*16 + uv)*256 + c] : 0  (pad rows)
// ---------------------------------------------------------------------------
__global__ void __launch_bounds__(256)
prep_all(const float* __restrict__ img,
         const float* __restrict__ mk_w1, const float* __restrict__ fh_w1,
         const float* __restrict__ mk_w2,
         unsigned short* __restrict__ imgT,
         unsigned short* __restrict__ w1f, unsigned short* __restrict__ w2a)
{
    __shared__ float s[128][65];
    const int b = blockIdx.x;
    if (b < 256) {
        const int n = b >> 6, h = b & 63;
        const float* src = img + (size_t)n * C_IN * HWSZ + h * 64;
        for (int i = threadIdx.x; i < 128 * 64; i += 256) {
            int ci = i >> 6, w = i & 63;
            s[ci][w] = src[(size_t)ci * HWSZ + w];
        }
        __syncthreads();
        unsigned short* dst = imgT + ((size_t)(n * 64 + h) * 64) * 128;
        for (int i = threadIdx.x; i < 64 * 128; i += 256) {
            int w = i >> 7, ci = i & 127;
            dst[(size_t)w * 128 + ci] = f2bf(s[ci][w]);
        }
        return;
    }
    int i = (b - 256) * 256 + threadIdx.x;
    if (i < 16 * 40960) {
        int uvt = i / 40960;
        int r   = i - uvt * 40960;
        int t   = r / 8192;
        int r2  = r - t * 8192;
        int ks16 = r2 >> 9;
        int lane = (r2 >> 3) & 63;
        int j    = r2 & 7;
        int k9 = t * 2 + ((lane >> 4) & 1);
        int uv = lane & 15;
        int c  = ks16 * 16 + (lane >> 5) * 8 + j;
        w2a[i] = (k9 < 9)
            ? f2bf(0.25f * mk_w2[((size_t)(k9 * 256 + uvt * 16 + uv)) * 256 + c])
            : (unsigned short)0;
    }
    if (i < 2 * 4 * 9 * 9 * 512) {
        int z   = i / 165888;
        int r   = i - z * 165888;
        int cc  = r / 41472;
        int r2  = r - cc * 41472;
        int tap = r2 / 4608;
        int r3  = r2 - tap * 4608;
        int g   = r3 / 512;
        int r4  = r3 - g * 512;
        int lane = r4 >> 3, j = r4 & 7;
        int lg = lane >> 4, ln = lane & 15;
        int row = g * 16 + ln;
        int ci  = cc * 32 + lg * 8 + j;
        float w = 0.f;
        if (z == 0) {
            if (row < 128)      w = mk_w1[((size_t)row * C_IN + ci) * 9 + tap];
            else if (row < 130) w = fh_w1[((size_t)(row - 128) * C_IN + ci) * 9 + tap];
        } else {
            if (row < 128)      w = mk_w1[((size_t)(128 + row) * C_IN + ci) * 9 + tap];
        }
        w1f[i] = f2bf(w);
    }
}

// ---------------------------------------------------------------------------
// K2: conv1 implicit-GEMM 3x3 (unchanged, known-good).
// ---------------------------------------------------------------------------
__global__ void __launch_bounds__(512, 4)
conv1_mfma(const unsigned short* __restrict__ imgT,
           const unsigned short* __restrict__ w1f,
           const float* __restrict__ mk_b1, const float* __restrict__ fh_b1,
           unsigned short* __restrict__ m_frag, float* __restrict__ h_pre,
           float* __restrict__ ps_s, float* __restrict__ ps_s2)
{
    __shared__ unsigned short s_img[3][66][40];
    __shared__ float s_bias[144];
    __shared__ float s_ps[2][144], s_ps2[2][144];

    const int hw = blockIdx.x;
    const int xcd = hw & 7, slot = hw >> 3;
    const int lid = xcd * 64 + slot;
    const int n = lid >> 7, h = (lid >> 1) & 63, z = lid & 1;
    const int hn = n * 64 + h;

    const int tid = threadIdx.x;
    const int wv = tid >> 6, lane = tid & 63;
    const int lg = lane >> 4, ln = lane & 15;
    const int gq = wv >> 1, half = wv & 1;
    const int g0 = z ? (gq * 2) : ((int[4]){0, 3, 5, 7})[gq];
    const int gn = z ? 2 : ((int[4]){3, 2, 2, 2})[gq];

    if (tid < 144) {
        float b = 0.f;
        if (z == 0) {
            if (tid < 128)      b = mk_b1[tid];
            else if (tid < 130) b = fh_b1[tid - 128];
        } else if (tid < 128)   b = mk_b1[128 + tid];
        s_bias[tid] = b;
    }

    f32x4 acc[3][2];
#pragma unroll
    for (int g = 0; g < 3; ++g)
#pragma unroll
        for (int q = 0; q < 2; ++q) acc[g][q] = (f32x4){0.f, 0.f, 0.f, 0.f};

    for (int cc = 0; cc < 4; ++cc) {
        __syncthreads();
        for (int i = tid; i < 3 * 66 * 4; i += 512) {
            int r = i / 264;
            int rem = i - r * 264;
            int c = rem >> 2, un = rem & 3;
            int gy = h - 1 + r, gx = c - 1;
            u16x8 v = {0, 0, 0, 0, 0, 0, 0, 0};
            if ((unsigned)gy < 64u && (unsigned)gx < 64u)
                v = *(const u16x8*)&imgT[((size_t)((n * 64 + gy) * 64 + gx)) * 128 + cc * 32 + un * 8];
            *(u16x8*)&s_img[r][c][un * 8] = v;
        }
        __syncthreads();

        const unsigned short* wfp = w1f + (size_t)(z * 4 + cc) * 81 * 512 + lane * 8;
#pragma unroll
        for (int tap = 0; tap < 9; ++tap) {
            const int dy = tap / 3, dx = tap % 3;
            s16x8 bf[2];
#pragma unroll
            for (int q = 0; q < 2; ++q)
                bf[q] = *(const s16x8*)&s_img[dy][half * 32 + q * 16 + ln + dx][lg * 8];
#pragma unroll
            for (int gi = 0; gi < 3; ++gi) {
                if (gi < gn) {
                    s16x8 af = *(const s16x8*)&wfp[(size_t)(tap * 9 + g0 + gi) * 512];
#pragma unroll
                    for (int q = 0; q < 2; ++q)
                        acc[gi][q] = __builtin_amdgcn_mfma_f32_16x16x32_bf16(af, bf[q], acc[gi][q], 0, 0, 0);
                }
            }
        }
    }

#pragma unroll
    for (int gi = 0; gi < 3; ++gi) {
        if (gi >= gn) continue;
        const int g = g0 + gi;
        float v[2][4];
#pragma unroll
        for (int q = 0; q < 2; ++q)
#pragma unroll
            for (int r = 0; r < 4; ++r)
                v[q][r] = acc[gi][q][r] + s_bias[g * 16 + lg * 4 + r];
#pragma unroll
        for (int q = 0; q < 2; ++q) {
            const int px  = half * 32 + q * 16 + ln;
            const int pxg = h * 4 + half * 2 + q;
            if (z == 0 && g == 8) {
                if (lg == 0) {
#pragma unroll
                    for (int r = 0; r < 2; ++r)
                        h_pre[((size_t)(n * 2 + r)) * HWSZ + h * 64 + px] = v[q][r];
                }
            } else {
                u16x4 vv;
#pragma unroll
                for (int r = 0; r < 4; ++r) vv[r] = f2bf(v[q][r]);
                int ks  = z * 4 + (g >> 1);
                int lgp = ((g & 1) * 2 + (lg >> 1)) & 3;
                size_t off = ((((size_t)(n * 256 + pxg) * 8 + ks) * 4 + lgp) * 128) + ln * 8 + (lg & 1) * 4;
                *(u16x4*)&m_frag[off] = vv;
            }
        }
#pragma unroll
        for (int r = 0; r < 4; ++r) {
            float s  = v[0][r] + v[1][r];
            float s2 = v[0][r] * v[0][r] + v[1][r] * v[1][r];
#pragma unroll
            for (int off = 1; off < 16; off <<= 1) {
                s  += __shfl_xor(s,  off, 64);
                s2 += __shfl_xor(s2, off, 64);
            }
            if (ln == 0) {
                s_ps[half][g * 16 + lg * 4 + r]  = s;
                s_ps2[half][g * 16 + lg * 4 + r] = s2;
            }
        }
    }
    __syncthreads();
    const int nch = z ? 128 : 130;
    if (tid < nch) {
        const int idx = z * 146 + tid;
        ps_s[(size_t)idx * 256 + hn]  = s_ps[0][tid] + s_ps[1][tid];
        ps_s2[(size_t)idx * 256 + hn] = s_ps2[0][tid] + s_ps2[1][tid];
    }
}

// ---------------------------------------------------------------------------
// K3: final BN stat reduction, one block per channel (258), 64 thr.
// ---------------------------------------------------------------------------
__global__ void __launch_bounds__(64)
bn_final2(const float* __restrict__ ps_s, const float* __restrict__ ps_s2,
          const float* __restrict__ mk_g, const float* __restrict__ mk_be,
          const float* __restrict__ fh_g, const float* __restrict__ fh_be,
          float* __restrict__ ab_m, float* __restrict__ ab_h)
{
    const int b = blockIdx.x;
    const int idx = (b < 256) ? ((b >> 7) * 146 + (b & 127)) : (128 + (b - 256));
    const int t = threadIdx.x;
    float S = 0.f, S2 = 0.f;
    const float* p1 = ps_s  + (size_t)idx * 256;
    const float* p2 = ps_s2 + (size_t)idx * 256;
    for (int i = t; i < 256; i += 64) { S += p1[i]; S2 += p2[i]; }
#pragma unroll
    for (int off = 32; off > 0; off >>= 1) {
        S += __shfl_down(S, off, 64); S2 += __shfl_down(S2, off, 64);
    }
    if (t == 0) {
        const float inv = 1.0f / (float)(N_B * HWSZ);
        float mu = S * inv;
        float var = S2 * inv - mu * mu;
        float r = rsqrtf(var + 1e-5f);
        if (b < 256) {
            float a = mk_g[b] * r;
            ab_m[2 * b] = a; ab_m[2 * b + 1] = mk_be[b] - mu * a;
        } else {
            int c = b - 256;
            float a = fh_g[c] * r;
            ab_h[2 * c] = a; ab_h[2 * c + 1] = fh_be[c] - mu * a;
        }
    }
}

// ---------------------------------------------------------------------------
// K4: blocks 0..2047 in-place BN+ReLU on m_frag; blocks 2048..2175 flow conv2.
// ---------------------------------------------------------------------------
__global__ void __launch_bounds__(256)
bnrelu_flow(unsigned short* __restrict__ m_frag, const float* __restrict__ ab,
            const float* __restrict__ hpre, const float* __restrict__ ab_h,
            const float* __restrict__ w2, const float* __restrict__ b2,
            float* __restrict__ flow8)
{
    __shared__ float s_ab[512];
    const int t = threadIdx.x;
    if (blockIdx.x < 2048) {
        s_ab[t] = ab[t]; s_ab[256 + t] = ab[256 + t];
        __syncthreads();
        const unsigned u = blockIdx.x * 256 + t;
        const int lg = (u >> 4) & 3, ks = (u >> 7) & 7;
        const int cb = ks * 32 + lg * 8;
        u16x8 v = *(const u16x8*)&m_frag[(size_t)u * 8];
        u16x8 o;
#pragma unroll
        for (int j = 0; j < 8; ++j) {
            float a = s_ab[2 * (cb + j)], b = s_ab[2 * (cb + j) + 1];
            o[j] = f2bf(fmaxf(a * bf2f(v[j]) + b, 0.f));
        }
        *(u16x8*)&m_frag[(size_t)u * 8] = o;
        return;
    }
    int idx = (blockIdx.x - 2048) * 256 + t;
    int w = idx & 63, h = (idx >> 6) & 63, co = (idx >> 12) & 1, n = idx >> 13;
    float acc = b2[co];
#pragma unroll
    for (int ci = 0; ci < 2; ++ci) {
        float a = ab_h[2 * ci], b = ab_h[2 * ci + 1];
        const float* p = hpre + (size_t)(n * 2 + ci) * HWSZ;
        const float* wp = &w2[(co * 2 + ci) * 9];
#pragma unroll
        for (int dy = 0; dy < 3; ++dy)
#pragma unroll
            for (int dx = 0; dx < 3; ++dx) {
                int gy = h + dy - 1, gx = w + dx - 1;
                float v = 0.f;
                if ((unsigned)gy < 64u && (unsigned)gx < 64u)
                    v = fmaxf(a * p[gy * 64 + gx] + b, 0.f);
                acc += wp[dy * 3 + dx] * v;
            }
    }
    flow8[idx] = acc * 8.0f;
}

// ---------------------------------------------------------------------------
// K5: fused 1x1-conv GEMM + softmax + convex upsample, 32x32x16 MFMA.
// R18: A-tile = 32 M-rows (2 k x 16 uv), 5 tiles (M 144->160 pad).
//  - acc[5] x f32x16 = 80 AGPR + ~30 VGPR ~= 110 < 128: fits (1024,4).
//  - af bytes/px halves vs 16x16 q=1 (2.5 KB vs 4.5 KB).
//  - C layout col=lane&31, row=(reg&3)+8(reg>>2)+4(lane>>5): each thread
//    holds ALL 9 k for its 8 uv -> softmax fully thread-local, no shfl.
//  - no-max exp (R16/R17-proven); pad rows k=9 never touched.
//  - 2 passes x 8 rows, cross-pass B prefetch, s_fl hoisted to 18 regs.
// LDS: s_w 80K + s_o 64K + s_fl 9.5K + bias 0.6K = 157.5 KB (1 block/CU).
// Grid 256 = (hg4+4n)%16 fast, uvt major -> 16 uvt blocks of one m-slice
// land on one XCD (FETCH-9MB-proven mapping).
// ---------------------------------------------------------------------------
__global__ void __launch_bounds__(1024, 4)
mask_combine_mfma(const unsigned short* __restrict__ m_frag,
                  const unsigned short* __restrict__ w2a,
                  const float* __restrict__ mk_b2,
                  const float* __restrict__ flow8,
                  float* __restrict__ out)
{
    __shared__ unsigned short s_w[40960];       // 81,920 B: [t5][ks16][lane64][j8]
    __shared__ float s_o[16384];                // 65,536 B: [c2][row8][1024]
    __shared__ float s_fl[2][18][66];           // 9,504 B
    __shared__ float s_bias[9][16];             // 576 B

    const int id = blockIdx.x;
    const int uvt = id >> 4, r4 = id & 15;
    const int hg = r4 & 3, n = r4 >> 2;

    const int tid = threadIdx.x;
    const int wv = tid >> 6, lane = tid & 63;
    const int row_l = wv >> 1, qhalf = wv & 1;      // 8 rows x 2 col-halves
    const int col = lane & 31, hi = lane >> 5;
    const int px = qhalf * 32 + col;                // 0..63

    // stage A tile (linear copy, 5120 x 16B)
    {
        const u16x8* wsrc = (const u16x8*)(w2a + (size_t)uvt * 40960);
        u16x8* wdst = (u16x8*)s_w;
        for (int i = tid; i < 5120; i += 1024) wdst[i] = wsrc[i];
    }
    // stage flow rows hg*16-1 .. hg*16+16
    for (int i = tid; i < 2 * 18 * 66; i += 1024) {
        int c = i / 1188, rem = i - c * 1188, r = rem / 66, cl = rem - r * 66;
        int gy = hg * 16 - 1 + r, gx = cl - 1;
        float v = 0.f;
        if ((unsigned)gy < 64u && (unsigned)gx < 64u)
            v = flow8[((size_t)(n * 2 + c)) * HWSZ + gy * 64 + gx];
        s_fl[c][r][cl] = v;
    }
    if (tid < 144) s_bias[tid >> 4][tid & 15] = 0.25f * mk_b2[(tid >> 4) * 256 + uvt * 16 + (tid & 15)];
    __syncthreads();

    // B base for pass 0: row h = hg*16 + row_l
    const int pxg0 = (hg * 16 + row_l) * 4 + qhalf * 2 + ((lane >> 4) & 1);
    const unsigned short* mb0 = m_frag + ((size_t)(n * 256 + pxg0)) * 4096
                              + hi * 128 + (lane & 15) * 8;

    // prime B prefetch (frag at ks16 = mb + ks16*256 elems)
    s16x8 bq[4];
#pragma unroll
    for (int d = 0; d < 4; ++d) bq[d] = *(const s16x8*)&mb0[d * 256];

    for (int pass = 0; pass < 2; ++pass) {
        const unsigned short* mb = mb0 + (size_t)pass * 131072;   // +8 rows

        f32x16 acc[5];
#pragma unroll
        for (int t = 0; t < 5; ++t)
#pragma unroll
            for (int e = 0; e < 16; ++e) acc[t][e] = 0.f;

#pragma unroll
        for (int ks16 = 0; ks16 < 16; ++ks16) {
            const int d = ks16 & 3;
#pragma unroll
            for (int t = 0; t < 5; ++t) {
                s16x8 af = *(const s16x8*)&s_w[(t * 16 + ks16) * 512 + lane * 8];
                acc[t] = __builtin_amdgcn_mfma_f32_32x32x16_bf16(af, bq[d], acc[t], 0, 0, 0);
            }
            if (ks16 < 12) bq[d] = *(const s16x8*)&mb[(ks16 + 4) * 256];
        }
        // cross-pass prefetch: hide next pass's B latency under epilogue VALU
        if (pass < 1) {
#pragma unroll
            for (int d = 0; d < 4; ++d)
                bq[d] = *(const s16x8*)&mb[131072 + d * 256];
        }

        // hoist flow taps for this thread's px (reused across all 8 uv)
        float fl0[9], fl1[9];
#pragma unroll
        for (int k = 0; k < 9; ++k) {
            const int dy = k / 3, dx = k % 3;
            fl0[k] = s_fl[0][pass * 8 + row_l + dy][px + dx];
            fl1[k] = s_fl[1][pass * 8 + row_l + dy][px + dx];
        }

        // thread-local softmax over 9 k for each of 8 uv
#pragma unroll
        for (int i = 0; i < 8; ++i) {
            const int uvl = hi * 4 + (i & 3) + 8 * (i >> 2);
            float sum = 0.f, a0 = 0.f, a1 = 0.f;
#pragma unroll
            for (int k = 0; k < 9; ++k) {
                const int reg = (i & 3) + 4 * (i >> 2) + 8 * (k & 1);
                float e = __expf(acc[k >> 1][reg] + s_bias[k][uvl]);
                sum += e;
                a0 += e * fl0[k];
                a1 += e * fl1[k];
            }
            float inv = 1.0f / sum;
            s_o[(0 * 8 + row_l) * 1024 + px * 16 + uvl] = a0 * inv;
            s_o[(1 * 8 + row_l) * 1024 + px * 16 + uvl] = a1 * inv;
        }
        __syncthreads();

        // cooperative lane-contiguous store: 16 rows x 4KB, fully dense.
        for (int i = tid; i < 4096; i += 1024) {
            const int idx = i * 4;
            const int row = idx >> 10;       // 0..15: c = row>>3, rl = row&7
            const int cl  = idx & 1023;
            const int c = row >> 3, rl = row & 7;
            f32x4 v = *(const f32x4*)&s_o[idx];
            *(f32x4*)(out + ((size_t)(n * 2 + c) * 1024 +
                             (hg * 16 + pass * 8 + rl) * 16 + uvt) * 1024 + cl) = v;
        }
        __syncthreads();   // protect s_o before next pass overwrites
    }
}

// ---------------------------------------------------------------------------
extern "C" void kernel_launch(void* const* d_in, const int* in_sizes, int n_in,
                              void* d_out, int out_size, void* d_ws, size_t ws_size,
                              hipStream_t stream) {
    const float* img   = (const float*)d_in[0];
    const float* fh_w1 = (const float*)d_in[1];
    const float* fh_b1 = (const float*)d_in[2];
    const float* fh_g  = (const float*)d_in[3];
    const float* fh_be = (const float*)d_in[4];
    const float* fh_w2 = (const float*)d_in[5];
    const float* fh_b2 = (const float*)d_in[6];
    const float* mk_w1 = (const float*)d_in[7];
    const float* mk_b1 = (const float*)d_in[8];
    const float* mk_g  = (const float*)d_in[9];
    const float* mk_be = (const float*)d_in[10];
    const float* mk_w2 = (const float*)d_in[11];
    const float* mk_b2 = (const float*)d_in[12];
    float* out = (float*)d_out;

    char* p = (char*)d_ws;
    unsigned short* w2a    = (unsigned short*)p;  p += (size_t)1310720;   // 16*40960*2
    unsigned short* w1f    = (unsigned short*)p;  p += (size_t)663552;
    unsigned short* imgT   = (unsigned short*)p;  p += (size_t)4194304;
    unsigned short* m_frag = (unsigned short*)p;  p += (size_t)8388608;
    float* h_pre  = (float*)p;  p += (size_t)131072;
    float* flow8  = (float*)p;  p += (size_t)131072;
    float* ps_s   = (float*)p;  p += (size_t)280576;
    float* ps_s2  = (float*)p;  p += (size_t)280576;
    float* ab_m   = (float*)p;  p += 2048;
    float* ab_h   = (float*)p;  p += 64;

    prep_all<<<2848, 256, 0, stream>>>(img, mk_w1, fh_w1, mk_w2, imgT, w1f, w2a);
    conv1_mfma<<<512, 512, 0, stream>>>(imgT, w1f, mk_b1, fh_b1, m_frag, h_pre, ps_s, ps_s2);
    bn_final2<<<258, 64, 0, stream>>>(ps_s, ps_s2, mk_g, mk_be, fh_g, fh_be, ab_m, ab_h);
    bnrelu_flow<<<2176, 256, 0, stream>>>(m_frag, ab_m, h_pre, ab_h, fh_w2, fh_b2, flow8);
    mask_combine_mfma<<<256, 1024, 0, stream>>>(m_frag, w2a, mk_b2, flow8, out);
}